// Round 9
// baseline (363.473 us; speedup 1.0000x reference)
//
#include <hip/hip_runtime.h>
#include <hip/hip_bf16.h>

#define NROW 8192
#define FINC 256
#define FOUTC 256
#define BM 64
#define BK 32
#define KSPLIT 8
#define KLOC (NROW / KSPLIT)   // 1024
#define NTL (KLOC / BK)        // 32 K-steps per block

typedef __attribute__((ext_vector_type(8))) short bf16x8;
typedef __attribute__((ext_vector_type(4))) float f32x4;

__device__ __forceinline__ unsigned short f2bf(float f) {
  unsigned u = __float_as_uint(f);
  u += 0x7fffu + ((u >> 16) & 1u);   // round-to-nearest-even
  return (unsigned short)(u >> 16);
}
__device__ __forceinline__ float bf2f(unsigned short h) {
  return __uint_as_float(((unsigned)h) << 16);
}

// ---- kernel 1: D[i] = 1/sqrt(1 + sum_j adj[i][j]); one wave per row ----
__global__ __launch_bounds__(256) void rowsum_kernel(const float* __restrict__ adj,
                                                     float* __restrict__ D) {
  const int row = blockIdx.x * 4 + (threadIdx.x >> 6);
  const int l = threadIdx.x & 63;
  const float4* p = reinterpret_cast<const float4*>(adj + (size_t)row * NROW);
  float s0 = 0.f, s1 = 0.f, s2 = 0.f, s3 = 0.f;
#pragma unroll
  for (int i = 0; i < 8; ++i) {
    float4 a = p[l + (i * 4 + 0) * 64];
    float4 b = p[l + (i * 4 + 1) * 64];
    float4 c = p[l + (i * 4 + 2) * 64];
    float4 d = p[l + (i * 4 + 3) * 64];
    s0 += (a.x + a.y) + (a.z + a.w);
    s1 += (b.x + b.y) + (b.z + b.w);
    s2 += (c.x + c.y) + (c.z + c.w);
    s3 += (d.x + d.y) + (d.z + d.w);
  }
  float s = (s0 + s1) + (s2 + s3);
#pragma unroll
  for (int off = 32; off > 0; off >>= 1) s += __shfl_down(s, off, 64);
  if (l == 0) D[row] = 1.0f / sqrtf(s + 1.0f);
}

// ---- kernel 2: s2T[f][j] = s2R[j][f] = bf16( D[j] * (x @ W)[j][f] ) ----
__global__ __launch_bounds__(256) void support_kernel(const float* __restrict__ x,
                                                      const float* __restrict__ W,
                                                      const float* __restrict__ D,
                                                      unsigned short* __restrict__ s2T,
                                                      unsigned short* __restrict__ s2R) {
  __shared__ float xs[32][FINC];
  const int t = threadIdx.x;
  const int r0 = blockIdx.x * 32;
  {
    const float4* xg = reinterpret_cast<const float4*>(x + (size_t)r0 * FINC);
    float4* xl = reinterpret_cast<float4*>(&xs[0][0]);
#pragma unroll
    for (int i = 0; i < 8; ++i) xl[t + i * 256] = xg[t + i * 256];
  }
  __syncthreads();
  const int w = t >> 6, l = t & 63;
  float acc[8][4] = {};
  const float4* W4 = reinterpret_cast<const float4*>(W);
#pragma unroll 4
  for (int k = 0; k < FINC; ++k) {
    float4 wv = W4[k * 64 + l];
#pragma unroll
    for (int m = 0; m < 8; ++m) {
      float xv = xs[w * 8 + m][k];
      acc[m][0] = fmaf(xv, wv.x, acc[m][0]);
      acc[m][1] = fmaf(xv, wv.y, acc[m][1]);
      acc[m][2] = fmaf(xv, wv.z, acc[m][2]);
      acc[m][3] = fmaf(xv, wv.w, acc[m][3]);
    }
  }
#pragma unroll
  for (int m = 0; m < 8; ++m) {
    const int j = r0 + w * 8 + m;
    const float d = D[j];
    const int f0 = l * 4;
    ushort4 rv;
    rv.x = f2bf(d * acc[m][0]);
    rv.y = f2bf(d * acc[m][1]);
    rv.z = f2bf(d * acc[m][2]);
    rv.w = f2bf(d * acc[m][3]);
    *reinterpret_cast<ushort4*>(&s2R[(size_t)j * FOUTC + f0]) = rv;
    s2T[(size_t)(f0 + 0) * NROW + j] = rv.x;
    s2T[(size_t)(f0 + 1) * NROW + j] = rv.y;
    s2T[(size_t)(f0 + 2) * NROW + j] = rv.z;
    s2T[(size_t)(f0 + 3) * NROW + j] = rv.w;
  }
}

// ---- kernel 3: K-split GEMM, TLP-first design.
// BM=64 x BN=256 x BK=32, KSPLIT=8 (ks = bid&7 -> one 512KB B-slice per XCD L2).
// LDS exactly 40960 B -> 3-4 blocks/CU; plain syncthreads dbuf (drains covered
// by co-resident blocks). A: 2-step 32B-contiguous bursts -> ds_write_b128.
// Swizzle: 16B-unit y stored at y ^ ((row>>1)&3)  => provably 2-way (free).
__global__ __launch_bounds__(512, 6) void gcn_gemm_kernel(const float* __restrict__ adj,
                                                          const unsigned short* __restrict__ s2T,
                                                          float* __restrict__ part) {
  __shared__ __align__(16) unsigned short As[2][BM * BK];      // 2 x 4 KB
  __shared__ __align__(16) unsigned short Bs[2][FOUTC * BK];   // 2 x 16 KB

  const int t = threadIdx.x, wid = t >> 6, l = t & 63;
  const int bid = blockIdx.x;
  const int m = bid >> 3, ks = bid & 7;
  const int bm0 = m * BM;
  const size_t k0 = (size_t)ks * KLOC;

  // A staging: thread -> row ar = t>>3, 8 threads/row; burst loads 32 B contiguous
  // (cols ac*8..ac*8+7 fp32 of a 2-step 64-col span). ac<4 holds even step, ac>=4 odd.
  const int ar = t >> 3, ac = t & 7;
  const float* aptr = adj + (size_t)(bm0 + ar) * NROW + k0 + ac * 8;
  const unsigned awoff = (unsigned)(ar * 64 + (((ac & 3) ^ ((ar >> 1) & 3)) << 4));

  // B staging via global_load_lds: chunk c = wid*2+i; lane l -> row c*16+(l>>2),
  // dest unit (l&3); source unit pre-XOR: (l&3) ^ ((l>>3)&3).
  const unsigned bsrc = (unsigned)(((l & 3) ^ ((l >> 3) & 3)) * 16);
  const int brow = l >> 2;

  f32x4 acc[2][4] = {};

  const int wm = wid >> 2, wn = wid & 3;     // 2M x 4N wave grid
  const int am0 = wm * 32, nb0 = wn * 64;
  const int fr = l & 15;
  // frag read offsets (bytes); +16 rows preserves (r>>1)&3 so offsets are +1024
  const unsigned aroff = (unsigned)((am0 + fr) * 64 +
                         ((((unsigned)(l >> 4)) ^ (((am0 + fr) >> 1) & 3)) << 4));
  const unsigned broff = (unsigned)((nb0 + fr) * 64 +
                         ((((unsigned)(l >> 4)) ^ (((nb0 + fr) >> 1) & 3)) << 4));

  auto stageB = [&](int kt, int sl) {
#pragma unroll
    for (int i = 0; i < 2; ++i) {
      const int c = wid * 2 + i;
      const unsigned short* src =
          s2T + (size_t)(c * 16 + brow) * NROW + k0 + (size_t)kt * BK;
      __builtin_amdgcn_global_load_lds(
          (const __attribute__((address_space(1))) unsigned int*)((const char*)src + bsrc),
          (__attribute__((address_space(3))) unsigned int*)((char*)&Bs[sl][0] + c * 1024),
          16, 0, 0);
    }
  };
  auto dsWriteA = [&](float4 v0, float4 v1, int sl) {
    bf16x8 u;
    u[0] = (short)f2bf(v0.x); u[1] = (short)f2bf(v0.y);
    u[2] = (short)f2bf(v0.z); u[3] = (short)f2bf(v0.w);
    u[4] = (short)f2bf(v1.x); u[5] = (short)f2bf(v1.y);
    u[6] = (short)f2bf(v1.z); u[7] = (short)f2bf(v1.w);
    *reinterpret_cast<bf16x8*>((char*)&As[sl][0] + awoff) = u;
  };
  auto compute = [&](int sl) {
    const char* Ab = (const char*)&As[sl][0];
    const char* Bb = (const char*)&Bs[sl][0];
    bf16x8 a0 = *reinterpret_cast<const bf16x8*>(Ab + aroff);
    bf16x8 a1 = *reinterpret_cast<const bf16x8*>(Ab + aroff + 1024);
#pragma unroll
    for (int n = 0; n < 4; ++n) {
      bf16x8 b = *reinterpret_cast<const bf16x8*>(Bb + broff + n * 1024);
      acc[0][n] = __builtin_amdgcn_mfma_f32_16x16x32_bf16(a0, b, acc[0][n], 0, 0, 0);
      acc[1][n] = __builtin_amdgcn_mfma_f32_16x16x32_bf16(a1, b, acc[1][n], 0, 0, 0);
    }
  };

  // ---- prologue: pair (0,1); write step 0; stage B(0) ----
  float4 v0 = *reinterpret_cast<const float4*>(aptr);
  float4 v1 = *reinterpret_cast<const float4*>(aptr + 4);
  stageB(0, 0);
  if (ac < 4) dsWriteA(v0, v1, 0);
  __syncthreads();

  // ---- main loop: 2 steps per trip ----
#pragma unroll 1
  for (int tt = 0; tt < NTL; tt += 2) {
    // even step tt: compute slot0; stage B(tt+1); write A step tt+1 (odd half)
    stageB(tt + 1, 1);
    compute(0);
    if (ac >= 4) dsWriteA(v0, v1, 1);
    __syncthreads();
    // odd step tt+1: compute slot1; burst pair (tt+2,tt+3); write A step tt+2
    if (tt + 2 < NTL) {
      float4 n0 = *reinterpret_cast<const float4*>(aptr + (tt + 2) * BK);
      float4 n1 = *reinterpret_cast<const float4*>(aptr + (tt + 2) * BK + 4);
      stageB(tt + 2, 0);
      compute(1);
      v0 = n0; v1 = n1;
      if (ac < 4) dsWriteA(v0, v1, 0);
    } else {
      compute(1);
    }
    __syncthreads();
  }

  // ---- epilogue: f32 partials; C/D layout col = l&15, row = (l>>4)*4 + q ----
  float* pout = part + (size_t)ks * NROW * FOUTC;
#pragma unroll
  for (int mm = 0; mm < 2; ++mm) {
#pragma unroll
    for (int n = 0; n < 4; ++n) {
#pragma unroll
      for (int q = 0; q < 4; ++q) {
        const int i = bm0 + am0 + mm * 16 + (l >> 4) * 4 + q;
        const int f = nb0 + n * 16 + fr;
        pout[(size_t)i * FOUTC + f] = acc[mm][n][q];
      }
    }
  }
}

// ---- kernel 4: out[i][f] = relu( (sum_ks part + s2R[i][f]) * D[i] + b[f] ) ----
__global__ __launch_bounds__(256) void combine_kernel(const float* __restrict__ part,
                                                      const unsigned short* __restrict__ s2R,
                                                      const float* __restrict__ D,
                                                      const float* __restrict__ bias,
                                                      float* __restrict__ out) {
  const int idx = blockIdx.x * 256 + threadIdx.x;   // one float4 per thread
  const int i = idx >> 6;
  const int f0 = (idx & 63) * 4;
  const size_t off = (size_t)i * FOUTC + f0;
  const size_t stride = (size_t)NROW * FOUTC;
  float4 s = *reinterpret_cast<const float4*>(part + off);
#pragma unroll
  for (int ks = 1; ks < KSPLIT; ++ks) {
    float4 p = *reinterpret_cast<const float4*>(part + (size_t)ks * stride + off);
    s.x += p.x; s.y += p.y; s.z += p.z; s.w += p.w;
  }
  ushort4 sv = *reinterpret_cast<const ushort4*>(s2R + off);
  float di = D[i];
  float4 bv = *reinterpret_cast<const float4*>(bias + f0);
  float4 o;
  o.x = fmaxf((s.x + bf2f(sv.x)) * di + bv.x, 0.f);
  o.y = fmaxf((s.y + bf2f(sv.y)) * di + bv.y, 0.f);
  o.z = fmaxf((s.z + bf2f(sv.z)) * di + bv.z, 0.f);
  o.w = fmaxf((s.w + bf2f(sv.w)) * di + bv.w, 0.f);
  *reinterpret_cast<float4*>(out + off) = o;
}

// ================= fallback path (round-3, used if ws too small) =============
__global__ __launch_bounds__(512) void gemm_fb(const float* __restrict__ adj,
                                               const unsigned short* __restrict__ s2T,
                                               const float* __restrict__ D,
                                               const float* __restrict__ bias,
                                               float* __restrict__ out) {
  __shared__ __align__(16) unsigned short Asf[3][32 * 64];
  __shared__ __align__(16) unsigned short Bsf[3][FOUTC * 64];
  const int t = threadIdx.x, wid = t >> 6, l = t & 63;
  const int bm0 = blockIdx.x * 32;
  const int ar = t >> 4;
  const unsigned awoff = (unsigned)(ar * 128 + (((t & 15) * 8) ^ ((ar & 7) << 4)));
  const float4* arow = reinterpret_cast<const float4*>(adj + (size_t)(bm0 + ar) * NROW) + (t & 15);
  const int bn = l >> 3;
  const unsigned bks = (unsigned)(((l & 7) * 16) ^ (bn << 4));
  f32x4 acc[2][2] = {};
  const unsigned swz = (unsigned)((l & 7) << 4);
  const int fr = l & 15;
  const unsigned kb = (unsigned)((l >> 4) * 16);
  const int nb = wid * 32;
  const int NTF = NROW / 64;
  auto stageB = [&](int kt, int sl) {
#pragma unroll
    for (int i = 0; i < 4; ++i) {
      const int c = wid * 4 + i;
      const int n = c * 8 + bn;
      const unsigned short* src = s2T + (size_t)n * NROW + (size_t)kt * 64;
      __builtin_amdgcn_global_load_lds(
          (const __attribute__((address_space(1))) unsigned int*)((const char*)src + bks),
          (__attribute__((address_space(3))) unsigned int*)((char*)&Bsf[sl][0] + c * 1024),
          16, 0, 0);
    }
  };
  auto writeA = [&](float4 av, int sl) {
    ushort4 ab;
    ab.x = f2bf(av.x); ab.y = f2bf(av.y); ab.z = f2bf(av.z); ab.w = f2bf(av.w);
    *reinterpret_cast<ushort4*>((char*)&Asf[sl][0] + awoff) = ab;
  };
  auto compute = [&](int sl) {
    const char* Ab = (const char*)&Asf[sl][0];
    const char* Bb = (const char*)&Bsf[sl][0];
#pragma unroll
    for (int kk = 0; kk < 2; ++kk) {
      const unsigned kx = ((unsigned)(kk * 64) + kb) ^ swz;
      bf16x8 a0 = *reinterpret_cast<const bf16x8*>(Ab + fr * 128 + kx);
      bf16x8 a1 = *reinterpret_cast<const bf16x8*>(Ab + (fr + 16) * 128 + kx);
      bf16x8 b0 = *reinterpret_cast<const bf16x8*>(Bb + (nb + fr) * 128 + kx);
      bf16x8 b1 = *reinterpret_cast<const bf16x8*>(Bb + (nb + 16 + fr) * 128 + kx);
      acc[0][0] = __builtin_amdgcn_mfma_f32_16x16x32_bf16(a0, b0, acc[0][0], 0, 0, 0);
      acc[0][1] = __builtin_amdgcn_mfma_f32_16x16x32_bf16(a0, b1, acc[0][1], 0, 0, 0);
      acc[1][0] = __builtin_amdgcn_mfma_f32_16x16x32_bf16(a1, b0, acc[1][0], 0, 0, 0);
      acc[1][1] = __builtin_amdgcn_mfma_f32_16x16x32_bf16(a1, b1, acc[1][1], 0, 0, 0);
    }
  };
  float4 a0p, a1p, a2p;
  {
    float4 a0v = arow[0];
    asm volatile("" ::: "memory");
    stageB(0, 0);
    a1p = arow[16];
    asm volatile("" ::: "memory");
    stageB(1, 1);
    a2p = arow[32];
    asm volatile("s_waitcnt vmcnt(10)" ::: "memory");
    writeA(a0v, 0);
  }
#define PIPE_ITER(KT, S0, S1, S2, AW, AN)                                      \
  asm volatile("s_waitcnt vmcnt(5) lgkmcnt(0)\n\ts_barrier" ::: "memory");     \
  writeA(AW, S1);                                                              \
  stageB((KT) + 2, S2);                                                        \
  if ((KT) < NTF - 3) AN = arow[((KT) + 3) * 16];                              \
  compute(S0);
#pragma unroll 1
  for (int kt = 0; kt < NTF - 2; kt += 3) {
    PIPE_ITER(kt + 0, 0, 1, 2, a1p, a0p)
    PIPE_ITER(kt + 1, 1, 2, 0, a2p, a1p)
    PIPE_ITER(kt + 2, 2, 0, 1, a0p, a2p)
  }
#undef PIPE_ITER
  asm volatile("s_waitcnt vmcnt(4) lgkmcnt(0)\n\ts_barrier" ::: "memory");
  writeA(a1p, 1);
  compute(0);
  asm volatile("s_waitcnt vmcnt(0) lgkmcnt(0)\n\ts_barrier" ::: "memory");
  compute(1);
#pragma unroll
  for (int m = 0; m < 2; ++m) {
#pragma unroll
    for (int n = 0; n < 2; ++n) {
#pragma unroll
      for (int q = 0; q < 4; ++q) {
        const int i = bm0 + m * 16 + (l >> 4) * 4 + q;
        const int f = wid * 32 + n * 16 + fr;
        const float selfv = bf2f(s2T[(size_t)f * NROW + i]);
        float v = (acc[m][n][q] + selfv) * D[i] + bias[f];
        out[(size_t)i * FOUTC + f] = fmaxf(v, 0.0f);
      }
    }
  }
}

extern "C" void kernel_launch(void* const* d_in, const int* in_sizes, int n_in,
                              void* d_out, int out_size, void* d_ws, size_t ws_size,
                              hipStream_t stream) {
  const float* x   = (const float*)d_in[0];
  const float* adj = (const float*)d_in[1];
  const float* W   = (const float*)d_in[2];
  const float* b   = (const float*)d_in[3];
  float* out = (float*)d_out;

  char* wsb = (char*)d_ws;
  float* D            = (float*)wsb;                                   // 32 KB
  unsigned short* s2T = (unsigned short*)(wsb + 32768);                // 4 MB [f][j]
  unsigned short* s2R = (unsigned short*)(wsb + 32768 + (1u << 22));   // 4 MB [j][f]
  float* part         = (float*)(wsb + 32768 + (2u << 22));            // 64 MB

  const size_t need = 32768ull + (2ull << 22) + (size_t)KSPLIT * NROW * FOUTC * 4ull;
  rowsum_kernel<<<NROW / 4, 256, 0, stream>>>(adj, D);
  support_kernel<<<NROW / 32, 256, 0, stream>>>(x, W, D, s2T, s2R);
  if (ws_size >= need) {
    gcn_gemm_kernel<<<(NROW / BM) * KSPLIT, 512, 0, stream>>>(adj, s2T, part);
    combine_kernel<<<NROW * FOUTC / 1024, 256, 0, stream>>>(part, s2R, D, b, out);
  } else {
    gemm_fb<<<NROW / 32, 512, 0, stream>>>(adj, s2T, D, b, out);
  }
}

// Round 10
// 199.760 us; speedup vs baseline: 1.8196x; 1.8196x over previous
//
#include <hip/hip_runtime.h>
#include <hip/hip_bf16.h>

#define NROW 8192
#define FINC 256
#define FOUTC 256
#define BM 64
#define BN 128
#define BK 64
#define KSPLIT 4
#define KLOC (NROW / KSPLIT)   // 2048
#define NTL (KLOC / BK)        // 32 K-steps per block

typedef __attribute__((ext_vector_type(8))) short bf16x8;
typedef __attribute__((ext_vector_type(4))) float f32x4;

__device__ __forceinline__ unsigned short f2bf(float f) {
  unsigned u = __float_as_uint(f);
  u += 0x7fffu + ((u >> 16) & 1u);   // round-to-nearest-even
  return (unsigned short)(u >> 16);
}
__device__ __forceinline__ float bf2f(unsigned short h) {
  return __uint_as_float(((unsigned)h) << 16);
}

// ---- kernel 1: D[i] = 1/sqrt(1 + sum_j adj[i][j]); one wave per row ----
__global__ __launch_bounds__(256) void rowsum_kernel(const float* __restrict__ adj,
                                                     float* __restrict__ D) {
  const int row = blockIdx.x * 4 + (threadIdx.x >> 6);
  const int l = threadIdx.x & 63;
  const float4* p = reinterpret_cast<const float4*>(adj + (size_t)row * NROW);
  float s0 = 0.f, s1 = 0.f, s2 = 0.f, s3 = 0.f;
#pragma unroll
  for (int i = 0; i < 8; ++i) {
    float4 a = p[l + (i * 4 + 0) * 64];
    float4 b = p[l + (i * 4 + 1) * 64];
    float4 c = p[l + (i * 4 + 2) * 64];
    float4 d = p[l + (i * 4 + 3) * 64];
    s0 += (a.x + a.y) + (a.z + a.w);
    s1 += (b.x + b.y) + (b.z + b.w);
    s2 += (c.x + c.y) + (c.z + c.w);
    s3 += (d.x + d.y) + (d.z + d.w);
  }
  float s = (s0 + s1) + (s2 + s3);
#pragma unroll
  for (int off = 32; off > 0; off >>= 1) s += __shfl_down(s, off, 64);
  if (l == 0) D[row] = 1.0f / sqrtf(s + 1.0f);
}

// ---- kernel 2: s2T[f][j] = s2R[j][f] = bf16( D[j] * (x @ W)[j][f] ) ----
__global__ __launch_bounds__(256) void support_kernel(const float* __restrict__ x,
                                                      const float* __restrict__ W,
                                                      const float* __restrict__ D,
                                                      unsigned short* __restrict__ s2T,
                                                      unsigned short* __restrict__ s2R) {
  __shared__ float xs[32][FINC];
  const int t = threadIdx.x;
  const int r0 = blockIdx.x * 32;
  {
    const float4* xg = reinterpret_cast<const float4*>(x + (size_t)r0 * FINC);
    float4* xl = reinterpret_cast<float4*>(&xs[0][0]);
#pragma unroll
    for (int i = 0; i < 8; ++i) xl[t + i * 256] = xg[t + i * 256];
  }
  __syncthreads();
  const int w = t >> 6, l = t & 63;
  float acc[8][4] = {};
  const float4* W4 = reinterpret_cast<const float4*>(W);
#pragma unroll 4
  for (int k = 0; k < FINC; ++k) {
    float4 wv = W4[k * 64 + l];
#pragma unroll
    for (int m = 0; m < 8; ++m) {
      float xv = xs[w * 8 + m][k];
      acc[m][0] = fmaf(xv, wv.x, acc[m][0]);
      acc[m][1] = fmaf(xv, wv.y, acc[m][1]);
      acc[m][2] = fmaf(xv, wv.z, acc[m][2]);
      acc[m][3] = fmaf(xv, wv.w, acc[m][3]);
    }
  }
#pragma unroll
  for (int m = 0; m < 8; ++m) {
    const int j = r0 + w * 8 + m;
    const float d = D[j];
    const int f0 = l * 4;
    ushort4 rv;
    rv.x = f2bf(d * acc[m][0]);
    rv.y = f2bf(d * acc[m][1]);
    rv.z = f2bf(d * acc[m][2]);
    rv.w = f2bf(d * acc[m][3]);
    *reinterpret_cast<ushort4*>(&s2R[(size_t)j * FOUTC + f0]) = rv;
    s2T[(size_t)(f0 + 0) * NROW + j] = rv.x;
    s2T[(size_t)(f0 + 1) * NROW + j] = rv.y;
    s2T[(size_t)(f0 + 2) * NROW + j] = rv.z;
    s2T[(size_t)(f0 + 3) * NROW + j] = rv.w;
  }
}

// ---- kernel 3: K-split GEMM, r8 schedule + 3 blocks/CU.
// BM=64 x BN=128 x BK=64, KSPLIT=4, N split in 2 halves. LDS = 48 KB -> 3
// blocks/CU. Twin blocks (same m,ks; different n-half) get bids equal mod 8
// and 8 apart -> same XCD, adjacent dispatch -> A-slice read once from HBM,
// twin hits L2. XCD x hosts only ks=x&3 -> 1 MB B slice L2-resident.
// Counted-vmcnt pipeline identical to r8 (W1=vmcnt(2), W2=vmcnt(4); never
// drains in main loop; one barrier per K-step).
__global__ __launch_bounds__(512, 6) void gcn_gemm_kernel(const float* __restrict__ adj,
                                                          const unsigned short* __restrict__ s2T,
                                                          float* __restrict__ part) {
  __shared__ __align__(16) unsigned short As[2][BM * BK];      // 2 x 8 KB, XOR-swizzled
  __shared__ __align__(16) unsigned short Bs[2][BN * BK];      // 2 x 16 KB, XOR-swizzled

  const int t = threadIdx.x, wid = t >> 6, l = t & 63;
  // bid -> (inner, nh): twins (inner,0)/(inner,1) differ by 8 in bid
  const int bid = blockIdx.x;
  const int x8 = bid & 7;
  const int nh = (bid >> 3) & 1;
  const int inner = (bid >> 4) * 8 + x8;     // 0..511
  const int m = inner >> 2, ks = inner & 3;  // XCD x8 sees ks = x8&3 only
  const int bm0 = m * BM;
  const size_t k0 = (size_t)ks * KLOC;

  // A staging: thread t -> row ar = t>>3, 8 threads/row, two float4 (32 B) each
  const int ar = t >> 3, ac = t & 7;
  const float4* arow = reinterpret_cast<const float4*>(adj + (size_t)(bm0 + ar) * NROW + k0) + ac;
  const unsigned awoff0 = (unsigned)(ar * 128 + ((ac * 8) ^ ((ar & 7) << 4)));
  const unsigned awoff1 = (unsigned)(ar * 128 + ((ac * 8 + 64) ^ ((ar & 7) << 4)));

  // B staging via global_load_lds: chunk c = wid*2+i; lane l -> row c*8+(l>>3),
  // pre-swizzled source kbyte (linear LDS dest + inverse-swz source, G21)
  const int bn = l >> 3;
  const unsigned bks = (unsigned)(((l & 7) * 16) ^ (bn << 4));

  f32x4 acc[2][2] = {};

  const int wm = wid >> 2, wn = wid & 3;     // 2M x 4N wave grid (32x32 per wave)
  const int am0 = wm * 32, nb0 = wn * 32;
  const unsigned swz = (unsigned)((l & 7) << 4);
  const int fr = l & 15;
  const unsigned kb = (unsigned)((l >> 4) * 16);

  auto stageB = [&](int kt, int sl) {
#pragma unroll
    for (int i = 0; i < 2; ++i) {
      const int c = wid * 2 + i;             // 16 chunks of 8 rows
      const int frow = nh * BN + c * 8 + bn;
      const unsigned short* src = s2T + (size_t)frow * NROW + k0 + (size_t)kt * BK;
      __builtin_amdgcn_global_load_lds(
          (const __attribute__((address_space(1))) unsigned int*)((const char*)src + bks),
          (__attribute__((address_space(3))) unsigned int*)((char*)&Bs[sl][0] + c * 1024),
          16, 0, 0);
    }
  };
  auto writeA = [&](float4 v0, float4 v1, int sl) {
    ushort4 u0, u1;
    u0.x = f2bf(v0.x); u0.y = f2bf(v0.y); u0.z = f2bf(v0.z); u0.w = f2bf(v0.w);
    u1.x = f2bf(v1.x); u1.y = f2bf(v1.y); u1.z = f2bf(v1.z); u1.w = f2bf(v1.w);
    *reinterpret_cast<ushort4*>((char*)&As[sl][0] + awoff0) = u0;
    *reinterpret_cast<ushort4*>((char*)&As[sl][0] + awoff1) = u1;
  };
  auto compute = [&](int sl) {
    const char* Ab = (const char*)&As[sl][0];
    const char* Bb = (const char*)&Bs[sl][0];
#pragma unroll
    for (int kk = 0; kk < 2; ++kk) {
      const unsigned kx = ((unsigned)(kk * 64) + kb) ^ swz;
      bf16x8 a0 = *reinterpret_cast<const bf16x8*>(Ab + (am0 + fr) * 128 + kx);
      bf16x8 a1 = *reinterpret_cast<const bf16x8*>(Ab + (am0 + 16 + fr) * 128 + kx);
      bf16x8 b0 = *reinterpret_cast<const bf16x8*>(Bb + (nb0 + fr) * 128 + kx);
      bf16x8 b1 = *reinterpret_cast<const bf16x8*>(Bb + (nb0 + 16 + fr) * 128 + kx);
      acc[0][0] = __builtin_amdgcn_mfma_f32_16x16x32_bf16(a0, b0, acc[0][0], 0, 0, 0);
      acc[0][1] = __builtin_amdgcn_mfma_f32_16x16x32_bf16(a0, b1, acc[0][1], 0, 0, 0);
      acc[1][0] = __builtin_amdgcn_mfma_f32_16x16x32_bf16(a1, b0, acc[1][0], 0, 0, 0);
      acc[1][1] = __builtin_amdgcn_mfma_f32_16x16x32_bf16(a1, b1, acc[1][1], 0, 0, 0);
    }
  };

  // ---- prologue: A(0)x2 | drain | writeA(0); B(0)x2; A(1)x2 -> 4 outstanding ----
  float4 aR0_0, aR0_1, aR1_0, aR1_1;
  {
    float4 v0 = arow[0], v1 = arow[8];
    asm volatile("s_waitcnt vmcnt(0)" ::: "memory");
    writeA(v0, v1, 0);
    stageB(0, 0);
    asm volatile("" ::: "memory");
    aR1_0 = arow[16]; aR1_1 = arow[24];
  }

  // ---- main loop: iter t: W1 vmcnt(2) -> B(t) landed (A(t+1) in flight);
  // issue B(t+1)x2 then A(t+2)x2; compute(t); W2 vmcnt(4) -> A(t+1) landed;
  // ds_write A(t+1) into slot (t+1)&1. Never drains below 2 in steady state. ----
#define GITER(T, SC, SN, AW0, AW1, AN0, AN1)                                   \
  asm volatile("s_waitcnt vmcnt(2) lgkmcnt(0)\n\ts_barrier" ::: "memory");     \
  stageB((T) + 1, SN);                                                         \
  asm volatile("" ::: "memory");                                               \
  AN0 = arow[((T) + 2) * 16]; AN1 = arow[((T) + 2) * 16 + 8];                  \
  compute(SC);                                                                 \
  asm volatile("s_waitcnt vmcnt(4)" ::: "memory");                             \
  writeA(AW0, AW1, SN);

#pragma unroll 1
  for (int tt = 0; tt < NTL - 2; tt += 2) {
    GITER(tt + 0, 0, 1, aR1_0, aR1_1, aR0_0, aR0_1)
    GITER(tt + 1, 1, 0, aR0_0, aR0_1, aR1_0, aR1_1)
  }
#undef GITER
  // t = NTL-2 (slot 0): stage B(NTL-1); A(NTL-1) lands mid-step
  asm volatile("s_waitcnt vmcnt(2) lgkmcnt(0)\n\ts_barrier" ::: "memory");
  stageB(NTL - 1, 1);
  compute(0);
  asm volatile("s_waitcnt vmcnt(2)" ::: "memory");   // A(NTL-1) landed
  writeA(aR1_0, aR1_1, 1);
  // t = NTL-1 (slot 1): drain
  asm volatile("s_waitcnt vmcnt(0) lgkmcnt(0)\n\ts_barrier" ::: "memory");
  compute(1);

  // ---- epilogue: f32 partials; C/D layout col = l&15, row = (l>>4)*4 + q ----
  float* pout = part + (size_t)ks * NROW * FOUTC;
#pragma unroll
  for (int mm = 0; mm < 2; ++mm) {
#pragma unroll
    for (int n = 0; n < 2; ++n) {
#pragma unroll
      for (int q = 0; q < 4; ++q) {
        const int i = bm0 + am0 + mm * 16 + (l >> 4) * 4 + q;
        const int f = nh * BN + nb0 + n * 16 + fr;
        pout[(size_t)i * FOUTC + f] = acc[mm][n][q];
      }
    }
  }
}

// ---- kernel 4: out[i][f] = relu( (sum_ks part + s2R[i][f]) * D[i] + b[f] ) ----
__global__ __launch_bounds__(256) void combine_kernel(const float* __restrict__ part,
                                                      const unsigned short* __restrict__ s2R,
                                                      const float* __restrict__ D,
                                                      const float* __restrict__ bias,
                                                      float* __restrict__ out) {
  const int idx = blockIdx.x * 256 + threadIdx.x;   // one float4 per thread
  const int i = idx >> 6;
  const int f0 = (idx & 63) * 4;
  const size_t off = (size_t)i * FOUTC + f0;
  const size_t stride = (size_t)NROW * FOUTC;
  float4 s = *reinterpret_cast<const float4*>(part + off);
#pragma unroll
  for (int ks = 1; ks < KSPLIT; ++ks) {
    float4 p = *reinterpret_cast<const float4*>(part + (size_t)ks * stride + off);
    s.x += p.x; s.y += p.y; s.z += p.z; s.w += p.w;
  }
  ushort4 sv = *reinterpret_cast<const ushort4*>(s2R + off);
  float di = D[i];
  float4 bv = *reinterpret_cast<const float4*>(bias + f0);
  float4 o;
  o.x = fmaxf((s.x + bf2f(sv.x)) * di + bv.x, 0.f);
  o.y = fmaxf((s.y + bf2f(sv.y)) * di + bv.y, 0.f);
  o.z = fmaxf((s.z + bf2f(sv.z)) * di + bv.z, 0.f);
  o.w = fmaxf((s.w + bf2f(sv.w)) * di + bv.w, 0.f);
  *reinterpret_cast<float4*>(out + off) = o;
}

// ================= fallback path (round-3, used if ws too small) =============
__global__ __launch_bounds__(512) void gemm_fb(const float* __restrict__ adj,
                                               const unsigned short* __restrict__ s2T,
                                               const float* __restrict__ D,
                                               const float* __restrict__ bias,
                                               float* __restrict__ out) {
  __shared__ __align__(16) unsigned short Asf[3][32 * 64];
  __shared__ __align__(16) unsigned short Bsf[3][FOUTC * 64];
  const int t = threadIdx.x, wid = t >> 6, l = t & 63;
  const int bm0 = blockIdx.x * 32;
  const int ar = t >> 4;
  const unsigned awoff = (unsigned)(ar * 128 + (((t & 15) * 8) ^ ((ar & 7) << 4)));
  const float4* arow = reinterpret_cast<const float4*>(adj + (size_t)(bm0 + ar) * NROW) + (t & 15);
  const int bn = l >> 3;
  const unsigned bks = (unsigned)(((l & 7) * 16) ^ (bn << 4));
  f32x4 acc[2][2] = {};
  const unsigned swz = (unsigned)((l & 7) << 4);
  const int fr = l & 15;
  const unsigned kb = (unsigned)((l >> 4) * 16);
  const int nb = wid * 32;
  const int NTF = NROW / 64;
  auto stageB = [&](int kt, int sl) {
#pragma unroll
    for (int i = 0; i < 4; ++i) {
      const int c = wid * 4 + i;
      const int n = c * 8 + bn;
      const unsigned short* src = s2T + (size_t)n * NROW + (size_t)kt * 64;
      __builtin_amdgcn_global_load_lds(
          (const __attribute__((address_space(1))) unsigned int*)((const char*)src + bks),
          (__attribute__((address_space(3))) unsigned int*)((char*)&Bsf[sl][0] + c * 1024),
          16, 0, 0);
    }
  };
  auto writeA = [&](float4 av, int sl) {
    ushort4 ab;
    ab.x = f2bf(av.x); ab.y = f2bf(av.y); ab.z = f2bf(av.z); ab.w = f2bf(av.w);
    *reinterpret_cast<ushort4*>((char*)&Asf[sl][0] + awoff) = ab;
  };
  auto compute = [&](int sl) {
    const char* Ab = (const char*)&Asf[sl][0];
    const char* Bb = (const char*)&Bsf[sl][0];
#pragma unroll
    for (int kk = 0; kk < 2; ++kk) {
      const unsigned kx = ((unsigned)(kk * 64) + kb) ^ swz;
      bf16x8 a0 = *reinterpret_cast<const bf16x8*>(Ab + fr * 128 + kx);
      bf16x8 a1 = *reinterpret_cast<const bf16x8*>(Ab + (fr + 16) * 128 + kx);
      bf16x8 b0 = *reinterpret_cast<const bf16x8*>(Bb + (nb + fr) * 128 + kx);
      bf16x8 b1 = *reinterpret_cast<const bf16x8*>(Bb + (nb + 16 + fr) * 128 + kx);
      acc[0][0] = __builtin_amdgcn_mfma_f32_16x16x32_bf16(a0, b0, acc[0][0], 0, 0, 0);
      acc[0][1] = __builtin_amdgcn_mfma_f32_16x16x32_bf16(a0, b1, acc[0][1], 0, 0, 0);
      acc[1][0] = __builtin_amdgcn_mfma_f32_16x16x32_bf16(a1, b0, acc[1][0], 0, 0, 0);
      acc[1][1] = __builtin_amdgcn_mfma_f32_16x16x32_bf16(a1, b1, acc[1][1], 0, 0, 0);
    }
  };
  float4 a0p, a1p, a2p;
  {
    float4 a0v = arow[0];
    asm volatile("" ::: "memory");
    stageB(0, 0);
    a1p = arow[16];
    asm volatile("" ::: "memory");
    stageB(1, 1);
    a2p = arow[32];
    asm volatile("s_waitcnt vmcnt(10)" ::: "memory");
    writeA(a0v, 0);
  }
#define PIPE_ITER(KT, S0, S1, S2, AW, AN)                                      \
  asm volatile("s_waitcnt vmcnt(5) lgkmcnt(0)\n\ts_barrier" ::: "memory");     \
  writeA(AW, S1);                                                              \
  stageB((KT) + 2, S2);                                                        \
  if ((KT) < NTF - 3) AN = arow[((KT) + 3) * 16];                              \
  compute(S0);
#pragma unroll 1
  for (int kt = 0; kt < NTF - 2; kt += 3) {
    PIPE_ITER(kt + 0, 0, 1, 2, a1p, a0p)
    PIPE_ITER(kt + 1, 1, 2, 0, a2p, a1p)
    PIPE_ITER(kt + 2, 2, 0, 1, a0p, a2p)
  }
#undef PIPE_ITER
  asm volatile("s_waitcnt vmcnt(4) lgkmcnt(0)\n\ts_barrier" ::: "memory");
  writeA(a1p, 1);
  compute(0);
  asm volatile("s_waitcnt vmcnt(0) lgkmcnt(0)\n\ts_barrier" ::: "memory");
  compute(1);
#pragma unroll
  for (int m = 0; m < 2; ++m) {
#pragma unroll
    for (int n = 0; n < 2; ++n) {
#pragma unroll
      for (int q = 0; q < 4; ++q) {
        const int i = bm0 + m * 16 + (l >> 4) * 4 + q;
        const int f = wid * 32 + n * 16 + fr;
        const float selfv = bf2f(s2T[(size_t)f * NROW + i]);
        float v = (acc[m][n][q] + selfv) * D[i] + bias[f];
        out[(size_t)i * FOUTC + f] = fmaxf(v, 0.0f);
      }
    }
  }
}

extern "C" void kernel_launch(void* const* d_in, const int* in_sizes, int n_in,
                              void* d_out, int out_size, void* d_ws, size_t ws_size,
                              hipStream_t stream) {
  const float* x   = (const float*)d_in[0];
  const float* adj = (const float*)d_in[1];
  const float* W   = (const float*)d_in[2];
  const float* b   = (const float*)d_in[3];
  float* out = (float*)d_out;

  char* wsb = (char*)d_ws;
  float* D            = (float*)wsb;                                   // 32 KB
  unsigned short* s2T = (unsigned short*)(wsb + 32768);                // 4 MB [f][j]
  unsigned short* s2R = (unsigned short*)(wsb + 32768 + (1u << 22));   // 4 MB [j][f]
  float* part         = (float*)(wsb + 32768 + (2u << 22));            // 32 MB

  const size_t need = 32768ull + (2ull << 22) + (size_t)KSPLIT * NROW * FOUTC * 4ull;
  rowsum_kernel<<<NROW / 4, 256, 0, stream>>>(adj, D);
  support_kernel<<<NROW / 32, 256, 0, stream>>>(x, W, D, s2T, s2R);
  if (ws_size >= need) {
    gcn_gemm_kernel<<<(NROW / BM) * KSPLIT * 2, 512, 0, stream>>>(adj, s2T, part);
    combine_kernel<<<NROW * FOUTC / 1024, 256, 0, stream>>>(part, s2R, D, b, out);
  } else {
    gemm_fb<<<NROW / 32, 512, 0, stream>>>(adj, s2T, D, b, out);
  }
}